// Round 16
// baseline (94.288 us; speedup 1.0000x reference)
//
#include <hip/hip_runtime.h>
#include <hip/hip_bf16.h>

// NT-Xent loss: B=4096, D=128, TEMP=0.5, N2=8192.
// loss = mean_i [ log sum_{j!=i} exp(2*sim_ij) - 2*pos_i ]
// sim = zn zn^T (bf16 MFMA), pos_i = fp32 cosine(z_i, z_{i^B}).
// Self-diagonal handled by rowsum seed = -exp2(sii_scaled).
//
// R16: ISOLATE THE ATOMICS. Every neutral variant (R5/R6/R11/R12/R13/R15)
// kept the 262k device-scope atomicAdds onto 512 rowsum lines; R14's
// removal test was sabotaged by its fence+counter tail (~135us). Clean
// test: R15 body verbatim, but partials go to part[cs][row] via PLAIN
// one-lane stores, summed in the EXISTING finalize kernel (no extra
// dispatch, no fences, no counters). If the end-of-kernel atomic drain
// was the residual, total drops ~10-15us; if neutral, atomics are
// exonerated and the plateau is declared next round.

#define BB 4096
#define N2 8192
#define DD 128
#define CSPLIT 32          // column splits (grid.x)
#define CW (N2 / CSPLIT)   // 256 cols per block
#define NCT (CW / 16)      // 16 col-tiles per block

// sqrt(2*log2(e)): zn scaled by this => A.B = 2*log2(e)*sim, so
// exp(2*sim) = exp2(A.B) directly.
#define SCALE 1.69864360f

#if __has_builtin(__builtin_amdgcn_exp2f)
#define EXP2F(x) __builtin_amdgcn_exp2f(x)
#else
#define EXP2F(x) __expf((x) * 0.6931471805599453f)
#endif

using bf16 = __hip_bfloat16;
typedef __attribute__((ext_vector_type(8))) short short8;   // MFMA A/B frag
typedef __attribute__((ext_vector_type(4))) float float4v;  // MFMA C/D frag

// Packed layout: tile t (16 rows of zn), chunk c (K-chunk of 32):
//   znP + (t*4 + c)*1024 + lane*16  holds  zn[t*16 + (lane&15)]
//                                          [c*32 + (lane>>4)*8 .. +7]
// i.e. exactly the short8 MFMA A/B fragment each lane needs.

// ---------------- Kernel 1: normalize + pack fragments ---------------------
__global__ __launch_bounds__(256) void ntx_norm_kernel(
    const float* __restrict__ zi, const float* __restrict__ zj,
    char* __restrict__ znP, float* __restrict__ rowsum,
    float* __restrict__ pos) {
  const int wave = threadIdx.x >> 6;
  const int lane = threadIdx.x & 63;
  const int pair = blockIdx.x * 4 + wave;   // 1024 blocks, 4 pairs/block
  float2 v = ((const float2*)(zi + (size_t)pair * DD))[lane];
  float2 w = ((const float2*)(zj + (size_t)pair * DD))[lane];
  float s1 = v.x * v.x + v.y * v.y;
  float s2 = w.x * w.x + w.y * w.y;
  float s3 = v.x * w.x + v.y * w.y;
  #pragma unroll
  for (int o = 32; o > 0; o >>= 1) {
    s1 += __shfl_xor(s1, o);
    s2 += __shfl_xor(s2, o);
    s3 += __shfl_xor(s3, o);
  }
  float nv = fmaxf(sqrtf(s1), 1e-8f);
  float nw = fmaxf(sqrtf(s2), 1e-8f);
  float rv = SCALE / nv, rw = SCALE / nw;   // scale folded into zn
  bf16 bx = __float2bfloat16(v.x * rv);
  bf16 by = __float2bfloat16(v.y * rv);
  bf16 cx = __float2bfloat16(w.x * rw);
  bf16 cy = __float2bfloat16(w.y * rw);
  __hip_bfloat162 h2; h2.x = bx; h2.y = by;   // elems 2*lane, 2*lane+1
  __hip_bfloat162 g2; g2.x = cx; g2.y = cy;   // same, row pair+BB
  unsigned hu = *(unsigned*)&h2;
  unsigned gu = *(unsigned*)&g2;

  // Pack: writer lane i (0..15) of each half emits elems 8i..8i+7 of its
  // row as one 16B chunk (c = i>>2, quad = i&3). Source u32 m lives in
  // lane 4i+m. All 64 lanes run the shfls (defined behavior).
  const int i = lane & 15;
  unsigned h0 = __shfl(hu, 4 * i + 0), g0 = __shfl(gu, 4 * i + 0);
  unsigned h1 = __shfl(hu, 4 * i + 1), g1 = __shfl(gu, 4 * i + 1);
  unsigned h2u = __shfl(hu, 4 * i + 2), g2u = __shfl(gu, 4 * i + 2);
  unsigned h3 = __shfl(hu, 4 * i + 3), g3 = __shfl(gu, 4 * i + 3);
  if (lane < 32) {
    const int r = (lane < 16) ? pair : (pair + BB);
    uint4 val;
    val.x = (lane < 16) ? h0 : g0;
    val.y = (lane < 16) ? h1 : g1;
    val.z = (lane < 16) ? h2u : g2u;
    val.w = (lane < 16) ? h3 : g3;
    // dest: tile r>>4, chunk i>>2, lane slot (i&3)*16 + (r&15)
    char* dst = znP + (((size_t)(r >> 4) * 4 + (i >> 2)) << 10) +
                ((((i & 3) << 4) + (r & 15)) << 4);
    *(uint4*)dst = val;
  }

  // self-dot in the SAME scaled bf16 precision the MFMA will see
  float fx = __bfloat162float(bx), fy = __bfloat162float(by);
  float gx = __bfloat162float(cx), gy = __bfloat162float(cy);
  float sii = fx * fx + fy * fy;            // = 2log2e * sim_ii (scaled)
  float sjj = gx * gx + gy * gy;
  #pragma unroll
  for (int o = 32; o > 0; o >>= 1) {
    sii += __shfl_xor(sii, o);
    sjj += __shfl_xor(sjj, o);
  }
  if (lane == 0) {
    float c = s3 / (nv * nw);               // fp32 positive-pair cosine
    rowsum[pair]      = -EXP2F(sii);        // diagonal seed (finalize adds)
    rowsum[pair + BB] = -EXP2F(sjj);
    pos[pair]      = c;
    pos[pair + BB] = c;
  }
}

// ---------------- Kernel 2: fused sim + sum-exp ----------------------------
// grid (32, 32). Block 256 = 4 waves; wave owns 64 rows (4 row-tiles),
// block owns 256 rows x 256 cols. All fragment loads coalesced from znP
// (base + lane*16). No LDS, no barriers, NO ATOMICS: partial row-sums go
// to part[cs][row] via plain stores. R0-style bn prefetch.
__global__ __launch_bounds__(256) void ntx_sim_kernel(
    const char* __restrict__ znP, float* __restrict__ part) {
  const int tid  = threadIdx.x;
  const int wave = tid >> 6;
  const int lane = tid & 63;
  const int quad = lane >> 4;
  const int l15  = lane & 15;

  const int rowBase = blockIdx.y * 256 + wave * 64;
  const int tile0   = blockIdx.x * NCT;      // first col-tile of this block

  // A fragments: 4 row-tiles x 4 K-chunks — coalesced packed loads
  const int art = (rowBase >> 4);            // first row-tile index
  short8 a[4][4];
  #pragma unroll
  for (int t = 0; t < 4; t++)
    #pragma unroll
    for (int c = 0; c < 4; c++)
      a[t][c] = *(const short8*)(znP + (((size_t)(art + t) * 4 + c) << 10) +
                                 lane * 16);
  // keep A resident (R10 pathology guard)
  asm volatile("" : "+v"(a[0][0]), "+v"(a[0][1]), "+v"(a[0][2]), "+v"(a[0][3]),
                    "+v"(a[1][0]), "+v"(a[1][1]), "+v"(a[1][2]), "+v"(a[1][3]),
                    "+v"(a[2][0]), "+v"(a[2][1]), "+v"(a[2][2]), "+v"(a[2][3]),
                    "+v"(a[3][0]), "+v"(a[3][1]), "+v"(a[3][2]), "+v"(a[3][3]));

  float rs[4][4];
  #pragma unroll
  for (int t = 0; t < 4; t++)
    #pragma unroll
    for (int r = 0; r < 4; r++) rs[t][r] = 0.0f;

  const char* bb = znP + ((size_t)tile0 << 12);   // 4 KB per tile

  short8 b[4];
  #pragma unroll
  for (int c = 0; c < 4; c++)
    b[c] = *(const short8*)(bb + (c << 10) + lane * 16);

  #pragma unroll 1
  for (int kt = 0; kt < NCT; kt++) {
    // prefetch next col-tile (coalesced; wraps on last iter — harmless)
    const int nkt = (kt + 1) & (NCT - 1);
    const char* bp = bb + ((size_t)nkt << 12);
    short8 bn[4];
    #pragma unroll
    for (int c = 0; c < 4; c++)
      bn[c] = *(const short8*)(bp + (c << 10) + lane * 16);

    #pragma unroll
    for (int t = 0; t < 4; t++) {
      float4v acc = {0.f, 0.f, 0.f, 0.f};
      acc = __builtin_amdgcn_mfma_f32_16x16x32_bf16(a[t][0], b[0], acc, 0, 0, 0);
      acc = __builtin_amdgcn_mfma_f32_16x16x32_bf16(a[t][1], b[1], acc, 0, 0, 0);
      acc = __builtin_amdgcn_mfma_f32_16x16x32_bf16(a[t][2], b[2], acc, 0, 0, 0);
      acc = __builtin_amdgcn_mfma_f32_16x16x32_bf16(a[t][3], b[3], acc, 0, 0, 0);
      // C/D: col = l15, row = quad*4 + r [m89/m91]; acc = 2log2e*sim.
      #pragma unroll
      for (int r = 0; r < 4; r++) rs[t][r] += EXP2F(acc[r]);
    }

    #pragma unroll
    for (int c = 0; c < 4; c++) b[c] = bn[c];
  }

  // reduce across the 16 lanes sharing each row, then ONE PLAIN STORE each
  float* myPart = part + (size_t)blockIdx.x * N2;
  #pragma unroll
  for (int t = 0; t < 4; t++) {
    #pragma unroll
    for (int r = 0; r < 4; r++) {
      float s = rs[t][r];
      s += __shfl_xor(s, 1);
      s += __shfl_xor(s, 2);
      s += __shfl_xor(s, 4);
      s += __shfl_xor(s, 8);
      if (l15 == 0)
        myPart[rowBase + t * 16 + quad * 4 + r] = s;
    }
  }
}

// ---------------- Kernel 3: finalize (sums the 32 partials per row) -------
__global__ __launch_bounds__(1024) void ntx_finalize_kernel(
    const float* __restrict__ rowsum, const float* __restrict__ part,
    const float* __restrict__ pos, float* __restrict__ out) {
  float s = 0.f;
  for (int i = threadIdx.x; i < N2; i += 1024) {
    float rsv = rowsum[i];                  // diagonal seed
    #pragma unroll
    for (int cs = 0; cs < CSPLIT; cs++)
      rsv += part[(size_t)cs * N2 + i];     // coalesced across threads
    s += __logf(rsv) - 2.0f * pos[i];
  }
  #pragma unroll
  for (int o = 32; o > 0; o >>= 1) s += __shfl_xor(s, o);
  __shared__ float sm[16];
  const int wave = threadIdx.x >> 6;
  const int lane = threadIdx.x & 63;
  if (lane == 0) sm[wave] = s;
  __syncthreads();
  if (threadIdx.x == 0) {
    float t = 0.f;
    #pragma unroll
    for (int i = 0; i < 16; i++) t += sm[i];
    out[0] = t / (float)N2;
  }
}

extern "C" void kernel_launch(void* const* d_in, const int* in_sizes, int n_in,
                              void* d_out, int out_size, void* d_ws, size_t ws_size,
                              hipStream_t stream) {
  const float* zi = (const float*)d_in[0];
  const float* zj = (const float*)d_in[1];
  float* out = (float*)d_out;

  char* ws = (char*)d_ws;
  char* znP = ws;                                         // 2 MB packed frags
  float* rowsum = (float*)(ws + (size_t)N2 * DD * 2);     // 32 KB (diag seed)
  float* pos = rowsum + N2;                               // 32 KB
  float* part = pos + N2;                                 // 32*8192*4 = 1 MB

  ntx_norm_kernel<<<BB / 4, 256, 0, stream>>>(zi, zj, znP, rowsum, pos);
  dim3 grid(CSPLIT, N2 / 256);
  ntx_sim_kernel<<<grid, 256, 0, stream>>>(znP, part);
  ntx_finalize_kernel<<<1, 1024, 0, stream>>>(rowsum, part, pos, out);
}

// Round 17
// 87.245 us; speedup vs baseline: 1.0807x; 1.0807x over previous
//
#include <hip/hip_runtime.h>
#include <hip/hip_bf16.h>

// NT-Xent loss: B=4096, D=128, TEMP=0.5, N2=8192.
// loss = mean_i [ log sum_{j!=i} exp(2*sim_ij) - 2*pos_i ]
// sim = zn zn^T (bf16 MFMA), pos_i = fp32 cosine(z_i, z_{i^B}).
// Self-diagonal handled by rowsum init = -exp2(sii_scaled).
//
// R17 (FINAL): restore R15, the best measured variant (89.0us). R16's
// atomic-free test was neutral-to-worse -> atomics exonerated, completing
// the falsification ledger: occupancy (R1-2,R7-11), barriers (R6),
// staging style (R5,R13,R15), wave coupling (R13), WORK VOLUME (R12:
// half MFMA+exp+LDS = same time), fragment reformat (R15), atomics (R16),
// fusion (R3,R4,R14: grid.sync ~50us, device fences ~135us — poison).
// Plateau ledger: fill 42us (harness re-poison, 80% HBM, untouchable) +
// gaps ~13us (harness) + norm/fin ~4us (BW-bound) + sim ~30us
// (structure-invariant across 12 falsification attempts; arithmetic
// floor ~9us unreachable by any evidenced mechanism).
//
// Kernel design (R15): norm kernel pre-packs zn into MFMA fragment order
// znP[tile][chunk][lane] via 8 shfls + one 16B store per writer lane.
// Sim loads BOTH A and B fragments as base + lane*16: perfectly
// coalesced, L2/L3-resident, ZERO LDS / barriers / swizzle / drains.
// Inner loop = R0's bn-prefetch shape. exp(2*sim) folded to exp2 via
// SCALE=sqrt(2*log2e) baked into zn.

#define BB 4096
#define N2 8192
#define DD 128
#define CSPLIT 32          // column splits (grid.x)
#define CW (N2 / CSPLIT)   // 256 cols per block
#define NCT (CW / 16)      // 16 col-tiles per block

// sqrt(2*log2(e)): zn scaled by this => A.B = 2*log2(e)*sim, so
// exp(2*sim) = exp2(A.B) directly.
#define SCALE 1.69864360f

#if __has_builtin(__builtin_amdgcn_exp2f)
#define EXP2F(x) __builtin_amdgcn_exp2f(x)
#else
#define EXP2F(x) __expf((x) * 0.6931471805599453f)
#endif

using bf16 = __hip_bfloat16;
typedef __attribute__((ext_vector_type(8))) short short8;   // MFMA A/B frag
typedef __attribute__((ext_vector_type(4))) float float4v;  // MFMA C/D frag

// Packed layout: tile t (16 rows of zn), chunk c (K-chunk of 32):
//   znP + (t*4 + c)*1024 + lane*16  holds  zn[t*16 + (lane&15)]
//                                          [c*32 + (lane>>4)*8 .. +7]
// i.e. exactly the short8 MFMA A/B fragment each lane needs.

// ---------------- Kernel 1: normalize + pack fragments ---------------------
__global__ __launch_bounds__(256) void ntx_norm_kernel(
    const float* __restrict__ zi, const float* __restrict__ zj,
    char* __restrict__ znP, float* __restrict__ rowsum,
    float* __restrict__ pos) {
  const int wave = threadIdx.x >> 6;
  const int lane = threadIdx.x & 63;
  const int pair = blockIdx.x * 4 + wave;   // 1024 blocks, 4 pairs/block
  float2 v = ((const float2*)(zi + (size_t)pair * DD))[lane];
  float2 w = ((const float2*)(zj + (size_t)pair * DD))[lane];
  float s1 = v.x * v.x + v.y * v.y;
  float s2 = w.x * w.x + w.y * w.y;
  float s3 = v.x * w.x + v.y * w.y;
  #pragma unroll
  for (int o = 32; o > 0; o >>= 1) {
    s1 += __shfl_xor(s1, o);
    s2 += __shfl_xor(s2, o);
    s3 += __shfl_xor(s3, o);
  }
  float nv = fmaxf(sqrtf(s1), 1e-8f);
  float nw = fmaxf(sqrtf(s2), 1e-8f);
  float rv = SCALE / nv, rw = SCALE / nw;   // scale folded into zn
  bf16 bx = __float2bfloat16(v.x * rv);
  bf16 by = __float2bfloat16(v.y * rv);
  bf16 cx = __float2bfloat16(w.x * rw);
  bf16 cy = __float2bfloat16(w.y * rw);
  __hip_bfloat162 h2; h2.x = bx; h2.y = by;   // elems 2*lane, 2*lane+1
  __hip_bfloat162 g2; g2.x = cx; g2.y = cy;   // same, row pair+BB
  unsigned hu = *(unsigned*)&h2;
  unsigned gu = *(unsigned*)&g2;

  // Pack: writer lane i (0..15) of each half emits elems 8i..8i+7 of its
  // row as one 16B chunk (c = i>>2, quad = i&3). Source u32 m lives in
  // lane 4i+m. All 64 lanes run the shfls (defined behavior).
  const int i = lane & 15;
  unsigned h0 = __shfl(hu, 4 * i + 0), g0 = __shfl(gu, 4 * i + 0);
  unsigned h1 = __shfl(hu, 4 * i + 1), g1 = __shfl(gu, 4 * i + 1);
  unsigned h2u = __shfl(hu, 4 * i + 2), g2u = __shfl(gu, 4 * i + 2);
  unsigned h3 = __shfl(hu, 4 * i + 3), g3 = __shfl(gu, 4 * i + 3);
  if (lane < 32) {
    const int r = (lane < 16) ? pair : (pair + BB);
    uint4 val;
    val.x = (lane < 16) ? h0 : g0;
    val.y = (lane < 16) ? h1 : g1;
    val.z = (lane < 16) ? h2u : g2u;
    val.w = (lane < 16) ? h3 : g3;
    // dest: tile r>>4, chunk i>>2, lane slot (i&3)*16 + (r&15)
    char* dst = znP + (((size_t)(r >> 4) * 4 + (i >> 2)) << 10) +
                ((((i & 3) << 4) + (r & 15)) << 4);
    *(uint4*)dst = val;
  }

  // self-dot in the SAME scaled bf16 precision the MFMA will see
  float fx = __bfloat162float(bx), fy = __bfloat162float(by);
  float gx = __bfloat162float(cx), gy = __bfloat162float(cy);
  float sii = fx * fx + fy * fy;            // = 2log2e * sim_ii (scaled)
  float sjj = gx * gx + gy * gy;
  #pragma unroll
  for (int o = 32; o > 0; o >>= 1) {
    sii += __shfl_xor(sii, o);
    sjj += __shfl_xor(sjj, o);
  }
  if (lane == 0) {
    float c = s3 / (nv * nw);               // fp32 positive-pair cosine
    rowsum[pair]      = -EXP2F(sii);        // cancels diagonal term
    rowsum[pair + BB] = -EXP2F(sjj);
    pos[pair]      = c;
    pos[pair + BB] = c;
  }
}

// ---------------- Kernel 2: fused sim + sum-exp ----------------------------
// grid (32, 32). Block 256 = 4 waves; wave owns 64 rows (4 row-tiles),
// block owns 256 rows x 256 cols. All fragment loads coalesced from znP
// (base + lane*16). No LDS, no barriers. R0-style bn prefetch.
__global__ __launch_bounds__(256) void ntx_sim_kernel(
    const char* __restrict__ znP, float* __restrict__ rowsum) {
  const int tid  = threadIdx.x;
  const int wave = tid >> 6;
  const int lane = tid & 63;
  const int quad = lane >> 4;
  const int l15  = lane & 15;

  const int rowBase = blockIdx.y * 256 + wave * 64;
  const int tile0   = blockIdx.x * NCT;      // first col-tile of this block

  // A fragments: 4 row-tiles x 4 K-chunks — coalesced packed loads
  const int art = (rowBase >> 4);            // first row-tile index
  short8 a[4][4];
  #pragma unroll
  for (int t = 0; t < 4; t++)
    #pragma unroll
    for (int c = 0; c < 4; c++)
      a[t][c] = *(const short8*)(znP + (((size_t)(art + t) * 4 + c) << 10) +
                                 lane * 16);
  // keep A resident (R10 pathology guard)
  asm volatile("" : "+v"(a[0][0]), "+v"(a[0][1]), "+v"(a[0][2]), "+v"(a[0][3]),
                    "+v"(a[1][0]), "+v"(a[1][1]), "+v"(a[1][2]), "+v"(a[1][3]),
                    "+v"(a[2][0]), "+v"(a[2][1]), "+v"(a[2][2]), "+v"(a[2][3]),
                    "+v"(a[3][0]), "+v"(a[3][1]), "+v"(a[3][2]), "+v"(a[3][3]));

  float rs[4][4];
  #pragma unroll
  for (int t = 0; t < 4; t++)
    #pragma unroll
    for (int r = 0; r < 4; r++) rs[t][r] = 0.0f;

  const char* bb = znP + ((size_t)tile0 << 12);   // 4 KB per tile

  short8 b[4];
  #pragma unroll
  for (int c = 0; c < 4; c++)
    b[c] = *(const short8*)(bb + (c << 10) + lane * 16);

  #pragma unroll 1
  for (int kt = 0; kt < NCT; kt++) {
    // prefetch next col-tile (coalesced; wraps on last iter — harmless)
    const int nkt = (kt + 1) & (NCT - 1);
    const char* bp = bb + ((size_t)nkt << 12);
    short8 bn[4];
    #pragma unroll
    for (int c = 0; c < 4; c++)
      bn[c] = *(const short8*)(bp + (c << 10) + lane * 16);

    #pragma unroll
    for (int t = 0; t < 4; t++) {
      float4v acc = {0.f, 0.f, 0.f, 0.f};
      acc = __builtin_amdgcn_mfma_f32_16x16x32_bf16(a[t][0], b[0], acc, 0, 0, 0);
      acc = __builtin_amdgcn_mfma_f32_16x16x32_bf16(a[t][1], b[1], acc, 0, 0, 0);
      acc = __builtin_amdgcn_mfma_f32_16x16x32_bf16(a[t][2], b[2], acc, 0, 0, 0);
      acc = __builtin_amdgcn_mfma_f32_16x16x32_bf16(a[t][3], b[3], acc, 0, 0, 0);
      // C/D: col = l15, row = quad*4 + r [m89/m91]; acc = 2log2e*sim.
      #pragma unroll
      for (int r = 0; r < 4; r++) rs[t][r] += EXP2F(acc[r]);
    }

    #pragma unroll
    for (int c = 0; c < 4; c++) b[c] = bn[c];
  }

  // reduce across the 16 lanes sharing each row, then one atomic each
  #pragma unroll
  for (int t = 0; t < 4; t++) {
    #pragma unroll
    for (int r = 0; r < 4; r++) {
      float s = rs[t][r];
      s += __shfl_xor(s, 1);
      s += __shfl_xor(s, 2);
      s += __shfl_xor(s, 4);
      s += __shfl_xor(s, 8);
      if (l15 == 0)
        atomicAdd(&rowsum[rowBase + t * 16 + quad * 4 + r], s);
    }
  }
}

// ---------------- Kernel 3: finalize --------------------------------------
__global__ __launch_bounds__(1024) void ntx_finalize_kernel(
    const float* __restrict__ rowsum, const float* __restrict__ pos,
    float* __restrict__ out) {
  float s = 0.f;
  for (int i = threadIdx.x; i < N2; i += 1024)
    s += __logf(rowsum[i]) - 2.0f * pos[i];
  #pragma unroll
  for (int o = 32; o > 0; o >>= 1) s += __shfl_xor(s, o);
  __shared__ float sm[16];
  const int wave = threadIdx.x >> 6;
  const int lane = threadIdx.x & 63;
  if (lane == 0) sm[wave] = s;
  __syncthreads();
  if (threadIdx.x == 0) {
    float t = 0.f;
    #pragma unroll
    for (int i = 0; i < 16; i++) t += sm[i];
    out[0] = t / (float)N2;
  }
}

extern "C" void kernel_launch(void* const* d_in, const int* in_sizes, int n_in,
                              void* d_out, int out_size, void* d_ws, size_t ws_size,
                              hipStream_t stream) {
  const float* zi = (const float*)d_in[0];
  const float* zj = (const float*)d_in[1];
  float* out = (float*)d_out;

  char* ws = (char*)d_ws;
  char* znP = ws;                                         // 2 MB packed frags
  float* rowsum = (float*)(ws + (size_t)N2 * DD * 2);     // 32 KB
  float* pos = rowsum + N2;                               // 32 KB

  ntx_norm_kernel<<<BB / 4, 256, 0, stream>>>(zi, zj, znP, rowsum, pos);
  dim3 grid(CSPLIT, N2 / 256);
  ntx_sim_kernel<<<grid, 256, 0, stream>>>(znP, rowsum);
  ntx_finalize_kernel<<<1, 1024, 0, stream>>>(rowsum, pos, out);
}